// Round 2
// baseline (539.910 us; speedup 1.0000x reference)
//
#include <hip/hip_runtime.h>
#include <math.h>

#define N_NODES 50000
#define N_EDGES 800000
#define IN_FEATS 128
#define N_HIDDEN 64
#define OUT_FEATS 40
#define DIM 8

// ---------------- CSR build step 1: zero in-degree counters ----------------
__global__ void zero_counts_kernel(int* __restrict__ counts) {
    int i = blockIdx.x * blockDim.x + threadIdx.x;
    if (i < N_NODES) counts[i] = 0;
}

// ---------------- CSR build step 2: in-degree histogram ----------------
__global__ void hist_kernel(const int* __restrict__ dst, int* __restrict__ counts) {
    int e = blockIdx.x * blockDim.x + threadIdx.x;
    if (e < N_EDGES) atomicAdd(&counts[dst[e]], 1);
}

// ---------------- CSR build step 3: single-block exclusive scan (50k) ----------------
__global__ __launch_bounds__(1024) void scan_kernel(const int* __restrict__ counts,
                                                    int* __restrict__ offsets,
                                                    int* __restrict__ cursor) {
    __shared__ int sums[1024];
    const int tid = threadIdx.x;
    const int CH = (N_NODES + 1023) / 1024;   // 49
    const int base = tid * CH;
    int local = 0;
    for (int i = 0; i < CH; ++i) {
        int idx = base + i;
        if (idx < N_NODES) local += counts[idx];
    }
    sums[tid] = local;
    __syncthreads();
    // Hillis-Steele inclusive scan over 1024 partial sums
    for (int off = 1; off < 1024; off <<= 1) {
        int v = 0;
        if (tid >= off) v = sums[tid - off];
        __syncthreads();
        sums[tid] += v;
        __syncthreads();
    }
    int run = sums[tid] - local;   // exclusive prefix of this thread's chunk
    for (int i = 0; i < CH; ++i) {
        int idx = base + i;
        if (idx < N_NODES) {
            offsets[idx] = run;
            cursor[idx]  = run;
            run += counts[idx];
        }
    }
    if (tid == 1023) offsets[N_NODES] = run;  // = N_EDGES
}

// ---------------- CSR build step 4: fill csr arrays + fused gaussian weights ----------------
__global__ void fill_kernel(const int* __restrict__ src, const int* __restrict__ dst,
                            const float* __restrict__ ew,
                            const float* __restrict__ mu1, const float* __restrict__ is1,
                            const float* __restrict__ mu2, const float* __restrict__ is2,
                            int* __restrict__ cursor,
                            int* __restrict__ csr_src,
                            float* __restrict__ csr_g1, float* __restrict__ csr_g2) {
    int e = blockIdx.x * blockDim.x + threadIdx.x;
    if (e >= N_EDGES) return;
    float s1 = 0.f, s2 = 0.f;
#pragma unroll
    for (int d = 0; d < DIM; ++d) {
        float v = ew[e * DIM + d];
        float d1 = v - mu1[d]; float a1 = is1[d];
        float d2 = v - mu2[d]; float a2 = is2[d];
        s1 += d1 * d1 * a1 * a1;
        s2 += d2 * d2 * a2 * a2;
    }
    int pos = atomicAdd(&cursor[dst[e]], 1);
    csr_src[pos] = src[e];
    csr_g1[pos]  = expf(-0.5f * s1);
    csr_g2[pos]  = expf(-0.5f * s2);
}

// ---------------- h1 = features @ W1  [N,128]x[128,64] ----------------
__global__ __launch_bounds__(64) void gemm1_kernel(const float* __restrict__ x,
                                                   const float* __restrict__ W,
                                                   float* __restrict__ h) {
    __shared__ float xs[IN_FEATS];
    int n = blockIdx.x;
    int t = threadIdx.x;
    xs[t]      = x[n * IN_FEATS + t];
    xs[t + 64] = x[n * IN_FEATS + t + 64];
    __syncthreads();
    float acc = 0.f;
#pragma unroll
    for (int k = 0; k < IN_FEATS; ++k)
        acc += xs[k] * W[k * N_HIDDEN + t];
    h[n * N_HIDDEN + t] = acc;
}

// ---------------- agg layer 1: gather-sum over dst-CSR, + b1 ----------------
// 256 threads = 4 waves; one wave per dst node; lane = feature (64)
__global__ __launch_bounds__(256) void agg1_kernel(const float* __restrict__ h,
                                                   const int* __restrict__ offsets,
                                                   const int* __restrict__ csr_src,
                                                   const float* __restrict__ csr_g,
                                                   const float* __restrict__ b,
                                                   float* __restrict__ x1) {
    int n = blockIdx.x * 4 + (threadIdx.x >> 6);
    int t = threadIdx.x & 63;
    if (n >= N_NODES) return;
    int beg = offsets[n], end = offsets[n + 1];
    float acc = 0.f;
    for (int j = beg; j < end; ++j) {
        int s   = csr_src[j];
        float g = csr_g[j];
        acc += h[s * N_HIDDEN + t] * g;
    }
    x1[n * N_HIDDEN + t] = acc + b[t];
}

// ---------------- h2 = x1 @ W2  [N,64]x[64,40] ----------------
__global__ __launch_bounds__(64) void gemm2_kernel(const float* __restrict__ x,
                                                   const float* __restrict__ W,
                                                   float* __restrict__ h) {
    __shared__ float xs[N_HIDDEN];
    int n = blockIdx.x;
    int t = threadIdx.x;
    xs[t] = x[n * N_HIDDEN + t];
    __syncthreads();
    if (t < OUT_FEATS) {
        float acc = 0.f;
#pragma unroll
        for (int k = 0; k < N_HIDDEN; ++k)
            acc += xs[k] * W[k * OUT_FEATS + t];
        h[n * OUT_FEATS + t] = acc;
    }
}

// ---------------- agg layer 2 + b2 + log_softmax fused ----------------
// 256 threads = 4 waves; one wave per dst node; lanes 0..39 = features
__global__ __launch_bounds__(256) void agg2_kernel(const float* __restrict__ h,
                                                   const int* __restrict__ offsets,
                                                   const int* __restrict__ csr_src,
                                                   const float* __restrict__ csr_g,
                                                   const float* __restrict__ b,
                                                   float* __restrict__ out) {
    int n = blockIdx.x * 4 + (threadIdx.x >> 6);
    int t = threadIdx.x & 63;
    if (n >= N_NODES) return;
    int beg = offsets[n], end = offsets[n + 1];
    float acc = 0.f;
    if (t < OUT_FEATS) {
        for (int j = beg; j < end; ++j) {
            int s   = csr_src[j];
            float g = csr_g[j];
            acc += h[s * OUT_FEATS + t] * g;
        }
        acc += b[t];
    }
    // log_softmax across the wave (lanes >= OUT_FEATS contribute -inf / 0)
    float v = (t < OUT_FEATS) ? acc : -INFINITY;
    float m = v;
#pragma unroll
    for (int off = 32; off; off >>= 1)
        m = fmaxf(m, __shfl_xor(m, off, 64));
    float ex = (t < OUT_FEATS) ? expf(v - m) : 0.f;
    float s = ex;
#pragma unroll
    for (int off = 32; off; off >>= 1)
        s += __shfl_xor(s, off, 64);
    if (t < OUT_FEATS)
        out[n * OUT_FEATS + t] = v - m - logf(s);
}

extern "C" void kernel_launch(void* const* d_in, const int* in_sizes, int n_in,
                              void* d_out, int out_size, void* d_ws, size_t ws_size,
                              hipStream_t stream) {
    const float* features    = (const float*)d_in[0];
    const float* edge_weight = (const float*)d_in[1];
    const int*   src         = (const int*)d_in[2];
    const int*   dst         = (const int*)d_in[3];
    const float* W1          = (const float*)d_in[4];
    const float* b1          = (const float*)d_in[5];
    const float* mu1         = (const float*)d_in[6];
    const float* is1         = (const float*)d_in[7];
    const float* W2          = (const float*)d_in[8];
    const float* b2          = (const float*)d_in[9];
    const float* mu2         = (const float*)d_in[10];
    const float* is2         = (const float*)d_in[11];
    float* out = (float*)d_out;

    // Workspace layout (4-byte elems):
    // h1[3.2M] x1[3.2M] h2[2M] csr_src[0.8M] csr_g1[0.8M] csr_g2[0.8M]
    // counts[50k] cursor[50k] offsets[50k+1]            total ≈ 44.6 MB
    float* ws = (float*)d_ws;
    float* h1      = ws;
    float* x1      = h1 + (size_t)N_NODES * N_HIDDEN;
    float* h2      = x1 + (size_t)N_NODES * N_HIDDEN;
    int*   csr_src = (int*)(h2 + (size_t)N_NODES * OUT_FEATS);
    float* csr_g1  = (float*)(csr_src + N_EDGES);
    float* csr_g2  = csr_g1 + N_EDGES;
    int*   counts  = (int*)(csr_g2 + N_EDGES);
    int*   cursor  = counts + N_NODES;
    int*   offsets = cursor + N_NODES;

    // ---- CSR build ----
    zero_counts_kernel<<<(N_NODES + 255) / 256, 256, 0, stream>>>(counts);
    hist_kernel<<<(N_EDGES + 255) / 256, 256, 0, stream>>>(dst, counts);
    scan_kernel<<<1, 1024, 0, stream>>>(counts, offsets, cursor);
    fill_kernel<<<(N_EDGES + 255) / 256, 256, 0, stream>>>(src, dst, edge_weight,
                                                           mu1, is1, mu2, is2,
                                                           cursor, csr_src, csr_g1, csr_g2);

    // ---- layer 1 ----
    gemm1_kernel<<<N_NODES, 64, 0, stream>>>(features, W1, h1);
    agg1_kernel<<<(N_NODES + 3) / 4, 256, 0, stream>>>(h1, offsets, csr_src, csr_g1, b1, x1);

    // ---- layer 2 + epilogue ----
    gemm2_kernel<<<N_NODES, 64, 0, stream>>>(x1, W2, h2);
    agg2_kernel<<<(N_NODES + 3) / 4, 256, 0, stream>>>(h2, offsets, csr_src, csr_g2, b2, out);
}

// Round 3
// 424.682 us; speedup vs baseline: 1.2713x; 1.2713x over previous
//
#include <hip/hip_runtime.h>
#include <math.h>

#define N_NODES 50000
#define N_EDGES 800000
#define IN_FEATS 128
#define N_HIDDEN 64
#define OUT_FEATS 40
#define DIM 8
#define SCAN_NB ((N_NODES + 255) / 256)   // 196

// ---------------- wave-wide inclusive scan (64 lanes) ----------------
__device__ __forceinline__ int wave_incl_scan(int x, int lane) {
#pragma unroll
    for (int off = 1; off < 64; off <<= 1) {
        int v = __shfl_up(x, off, 64);
        if (lane >= off) x += v;
    }
    return x;
}

// ---------------- CSR build: in-degree histogram ----------------
__global__ void hist_kernel(const int* __restrict__ dst, int* __restrict__ counts) {
    int e = blockIdx.x * blockDim.x + threadIdx.x;
    if (e < N_EDGES) atomicAdd(&counts[dst[e]], 1);
}

// ---------------- scan phase 1: block-local exclusive scan + block totals ----------------
__global__ __launch_bounds__(256) void scan_blk_kernel(const int* __restrict__ counts,
                                                       int* __restrict__ offsets,
                                                       int* __restrict__ blkSums) {
    int i = blockIdx.x * 256 + threadIdx.x;
    int lane = threadIdx.x & 63, wid = threadIdx.x >> 6;
    int x = (i < N_NODES) ? counts[i] : 0;
    int incl = wave_incl_scan(x, lane);
    __shared__ int wsum[4];
    if (lane == 63) wsum[wid] = incl;
    __syncthreads();
    int base = 0;
#pragma unroll
    for (int w = 0; w < 4; ++w)
        if (w < wid) base += wsum[w];
    if (i < N_NODES) offsets[i] = base + incl - x;     // block-local exclusive
    if (threadIdx.x == 255) blkSums[blockIdx.x] = base + incl;  // block total
}

// ---------------- scan phase 2: exclusive scan of 196 block totals ----------------
__global__ __launch_bounds__(256) void scan_top_kernel(int* __restrict__ blkSums) {
    int i = threadIdx.x;
    int lane = i & 63, wid = i >> 6;
    int x = (i < SCAN_NB) ? blkSums[i] : 0;
    int incl = wave_incl_scan(x, lane);
    __shared__ int wsum[4];
    if (lane == 63) wsum[wid] = incl;
    __syncthreads();
    int base = 0;
#pragma unroll
    for (int w = 0; w < 4; ++w)
        if (w < wid) base += wsum[w];
    if (i < SCAN_NB) blkSums[i] = base + incl - x;     // exclusive
}

// ---------------- scan phase 3: add block bases, emit offsets + cursor ----------------
__global__ __launch_bounds__(256) void scan_add_kernel(int* __restrict__ offsets,
                                                       const int* __restrict__ blkSums,
                                                       int* __restrict__ cursor) {
    int i = blockIdx.x * 256 + threadIdx.x;
    if (i < N_NODES) {
        int v = offsets[i] + blkSums[blockIdx.x];
        offsets[i] = v;
        cursor[i]  = v;
    }
    if (blockIdx.x == 0 && threadIdx.x == 0)
        offsets[N_NODES] = N_EDGES;
}

// ---------------- CSR fill + fused gaussian weights ----------------
__global__ void fill_kernel(const int* __restrict__ src, const int* __restrict__ dst,
                            const float* __restrict__ ew,
                            const float* __restrict__ mu1, const float* __restrict__ is1,
                            const float* __restrict__ mu2, const float* __restrict__ is2,
                            int* __restrict__ cursor,
                            int* __restrict__ csr_src,
                            float* __restrict__ csr_g1, float* __restrict__ csr_g2) {
    int e = blockIdx.x * blockDim.x + threadIdx.x;
    if (e >= N_EDGES) return;
    float s1 = 0.f, s2 = 0.f;
#pragma unroll
    for (int d = 0; d < DIM; ++d) {
        float v = ew[e * DIM + d];
        float d1 = v - mu1[d]; float a1 = is1[d];
        float d2 = v - mu2[d]; float a2 = is2[d];
        s1 += d1 * d1 * a1 * a1;
        s2 += d2 * d2 * a2 * a2;
    }
    int pos = atomicAdd(&cursor[dst[e]], 1);
    csr_src[pos] = src[e];
    csr_g1[pos]  = expf(-0.5f * s1);
    csr_g2[pos]  = expf(-0.5f * s2);
}

// ---------------- h1 = features @ W1  [N,128]x[128,64] ----------------
__global__ __launch_bounds__(64) void gemm1_kernel(const float* __restrict__ x,
                                                   const float* __restrict__ W,
                                                   float* __restrict__ h) {
    __shared__ float xs[IN_FEATS];
    int n = blockIdx.x;
    int t = threadIdx.x;
    xs[t]      = x[n * IN_FEATS + t];
    xs[t + 64] = x[n * IN_FEATS + t + 64];
    __syncthreads();
    float acc = 0.f;
#pragma unroll
    for (int k = 0; k < IN_FEATS; ++k)
        acc += xs[k] * W[k * N_HIDDEN + t];
    h[n * N_HIDDEN + t] = acc;
}

// ---------------- agg layer 1: gather-sum over dst-CSR, + b1 ----------------
__global__ __launch_bounds__(256) void agg1_kernel(const float* __restrict__ h,
                                                   const int* __restrict__ offsets,
                                                   const int* __restrict__ csr_src,
                                                   const float* __restrict__ csr_g,
                                                   const float* __restrict__ b,
                                                   float* __restrict__ x1) {
    int n = blockIdx.x * 4 + (threadIdx.x >> 6);
    int t = threadIdx.x & 63;
    if (n >= N_NODES) return;
    int beg = offsets[n], end = offsets[n + 1];
    float acc = 0.f;
    for (int j = beg; j < end; ++j) {
        int s   = csr_src[j];
        float g = csr_g[j];
        acc += h[s * N_HIDDEN + t] * g;
    }
    x1[n * N_HIDDEN + t] = acc + b[t];
}

// ---------------- h2 = x1 @ W2  [N,64]x[64,40] ----------------
__global__ __launch_bounds__(64) void gemm2_kernel(const float* __restrict__ x,
                                                   const float* __restrict__ W,
                                                   float* __restrict__ h) {
    __shared__ float xs[N_HIDDEN];
    int n = blockIdx.x;
    int t = threadIdx.x;
    xs[t] = x[n * N_HIDDEN + t];
    __syncthreads();
    if (t < OUT_FEATS) {
        float acc = 0.f;
#pragma unroll
        for (int k = 0; k < N_HIDDEN; ++k)
            acc += xs[k] * W[k * OUT_FEATS + t];
        h[n * OUT_FEATS + t] = acc;
    }
}

// ---------------- agg layer 2 + b2 + log_softmax fused ----------------
__global__ __launch_bounds__(256) void agg2_kernel(const float* __restrict__ h,
                                                   const int* __restrict__ offsets,
                                                   const int* __restrict__ csr_src,
                                                   const float* __restrict__ csr_g,
                                                   const float* __restrict__ b,
                                                   float* __restrict__ out) {
    int n = blockIdx.x * 4 + (threadIdx.x >> 6);
    int t = threadIdx.x & 63;
    if (n >= N_NODES) return;
    int beg = offsets[n], end = offsets[n + 1];
    float acc = 0.f;
    if (t < OUT_FEATS) {
        for (int j = beg; j < end; ++j) {
            int s   = csr_src[j];
            float g = csr_g[j];
            acc += h[s * OUT_FEATS + t] * g;
        }
        acc += b[t];
    }
    float v = (t < OUT_FEATS) ? acc : -INFINITY;
    float m = v;
#pragma unroll
    for (int off = 32; off; off >>= 1)
        m = fmaxf(m, __shfl_xor(m, off, 64));
    float ex = (t < OUT_FEATS) ? expf(v - m) : 0.f;
    float s = ex;
#pragma unroll
    for (int off = 32; off; off >>= 1)
        s += __shfl_xor(s, off, 64);
    if (t < OUT_FEATS)
        out[n * OUT_FEATS + t] = v - m - logf(s);
}

extern "C" void kernel_launch(void* const* d_in, const int* in_sizes, int n_in,
                              void* d_out, int out_size, void* d_ws, size_t ws_size,
                              hipStream_t stream) {
    const float* features    = (const float*)d_in[0];
    const float* edge_weight = (const float*)d_in[1];
    const int*   src         = (const int*)d_in[2];
    const int*   dst         = (const int*)d_in[3];
    const float* W1          = (const float*)d_in[4];
    const float* b1          = (const float*)d_in[5];
    const float* mu1         = (const float*)d_in[6];
    const float* is1         = (const float*)d_in[7];
    const float* W2          = (const float*)d_in[8];
    const float* b2          = (const float*)d_in[9];
    const float* mu2         = (const float*)d_in[10];
    const float* is2         = (const float*)d_in[11];
    float* out = (float*)d_out;

    // Workspace layout (4-byte elems):
    // h1[3.2M] x1[3.2M] h2[2M] csr_src[0.8M] csr_g1[0.8M] csr_g2[0.8M]
    // counts[50k] cursor[50k] offsets[50k+1] blkSums[196]
    float* ws = (float*)d_ws;
    float* h1      = ws;
    float* x1      = h1 + (size_t)N_NODES * N_HIDDEN;
    float* h2      = x1 + (size_t)N_NODES * N_HIDDEN;
    int*   csr_src = (int*)(h2 + (size_t)N_NODES * OUT_FEATS);
    float* csr_g1  = (float*)(csr_src + N_EDGES);
    float* csr_g2  = csr_g1 + N_EDGES;
    int*   counts  = (int*)(csr_g2 + N_EDGES);
    int*   cursor  = counts + N_NODES;
    int*   offsets = cursor + N_NODES;
    int*   blkSums = offsets + N_NODES + 1;

    // ---- CSR build ----
    hipMemsetAsync(counts, 0, N_NODES * sizeof(int), stream);
    hist_kernel<<<(N_EDGES + 255) / 256, 256, 0, stream>>>(dst, counts);
    scan_blk_kernel<<<SCAN_NB, 256, 0, stream>>>(counts, offsets, blkSums);
    scan_top_kernel<<<1, 256, 0, stream>>>(blkSums);
    scan_add_kernel<<<SCAN_NB, 256, 0, stream>>>(offsets, blkSums, cursor);
    fill_kernel<<<(N_EDGES + 255) / 256, 256, 0, stream>>>(src, dst, edge_weight,
                                                           mu1, is1, mu2, is2,
                                                           cursor, csr_src, csr_g1, csr_g2);

    // ---- layer 1 ----
    gemm1_kernel<<<N_NODES, 64, 0, stream>>>(features, W1, h1);
    agg1_kernel<<<(N_NODES + 3) / 4, 256, 0, stream>>>(h1, offsets, csr_src, csr_g1, b1, x1);

    // ---- layer 2 + epilogue ----
    gemm2_kernel<<<N_NODES, 64, 0, stream>>>(x1, W2, h2);
    agg2_kernel<<<(N_NODES + 3) / 4, 256, 0, stream>>>(h2, offsets, csr_src, csr_g2, b2, out);
}

// Round 4
// 334.895 us; speedup vs baseline: 1.6122x; 1.2681x over previous
//
#include <hip/hip_runtime.h>
#include <math.h>

#define N_NODES 50000
#define N_EDGES 800000
#define IN_FEATS 128
#define N_HIDDEN 64
#define OUT_FEATS 40
#define DIM 8
#define SCAN_NB ((N_NODES + 255) / 256)   // 196

// ---------------- wave-wide inclusive scan (64 lanes) ----------------
__device__ __forceinline__ int wave_incl_scan(int x, int lane) {
#pragma unroll
    for (int off = 1; off < 64; off <<= 1) {
        int v = __shfl_up(x, off, 64);
        if (lane >= off) x += v;
    }
    return x;
}

// ---------------- CSR build: in-degree histogram ----------------
__global__ void hist_kernel(const int* __restrict__ dst, int* __restrict__ counts) {
    int e = blockIdx.x * blockDim.x + threadIdx.x;
    if (e < N_EDGES) atomicAdd(&counts[dst[e]], 1);
}

// ---------------- scan phase 1: block-local exclusive scan + block totals ----------------
__global__ __launch_bounds__(256) void scan_blk_kernel(const int* __restrict__ counts,
                                                       int* __restrict__ offsets,
                                                       int* __restrict__ blkSums) {
    int i = blockIdx.x * 256 + threadIdx.x;
    int lane = threadIdx.x & 63, wid = threadIdx.x >> 6;
    int x = (i < N_NODES) ? counts[i] : 0;
    int incl = wave_incl_scan(x, lane);
    __shared__ int wsum[4];
    if (lane == 63) wsum[wid] = incl;
    __syncthreads();
    int base = 0;
#pragma unroll
    for (int w = 0; w < 4; ++w)
        if (w < wid) base += wsum[w];
    if (i < N_NODES) offsets[i] = base + incl - x;     // block-local exclusive
    if (threadIdx.x == 255) blkSums[blockIdx.x] = base + incl;  // block total
}

// ---------------- scan phase 2: exclusive scan of 196 block totals ----------------
__global__ __launch_bounds__(256) void scan_top_kernel(int* __restrict__ blkSums) {
    int i = threadIdx.x;
    int lane = i & 63, wid = i >> 6;
    int x = (i < SCAN_NB) ? blkSums[i] : 0;
    int incl = wave_incl_scan(x, lane);
    __shared__ int wsum[4];
    if (lane == 63) wsum[wid] = incl;
    __syncthreads();
    int base = 0;
#pragma unroll
    for (int w = 0; w < 4; ++w)
        if (w < wid) base += wsum[w];
    if (i < SCAN_NB) blkSums[i] = base + incl - x;     // exclusive
}

// ---------------- scan phase 3: add block bases, emit offsets + cursor ----------------
__global__ __launch_bounds__(256) void scan_add_kernel(int* __restrict__ offsets,
                                                       const int* __restrict__ blkSums,
                                                       int* __restrict__ cursor) {
    int i = blockIdx.x * 256 + threadIdx.x;
    if (i < N_NODES) {
        int v = offsets[i] + blkSums[blockIdx.x];
        offsets[i] = v;
        cursor[i]  = v;
    }
    if (blockIdx.x == 0 && threadIdx.x == 0)
        offsets[N_NODES] = N_EDGES;
}

// ---------------- CSR fill + fused gaussian weights ----------------
__global__ void fill_kernel(const int* __restrict__ src, const int* __restrict__ dst,
                            const float* __restrict__ ew,
                            const float* __restrict__ mu1, const float* __restrict__ is1,
                            const float* __restrict__ mu2, const float* __restrict__ is2,
                            int* __restrict__ cursor,
                            int* __restrict__ csr_src,
                            float* __restrict__ csr_g1, float* __restrict__ csr_g2) {
    int e = blockIdx.x * blockDim.x + threadIdx.x;
    if (e >= N_EDGES) return;
    float s1 = 0.f, s2 = 0.f;
#pragma unroll
    for (int d = 0; d < DIM; ++d) {
        float v = ew[e * DIM + d];
        float d1 = v - mu1[d]; float a1 = is1[d];
        float d2 = v - mu2[d]; float a2 = is2[d];
        s1 += d1 * d1 * a1 * a1;
        s2 += d2 * d2 * a2 * a2;
    }
    int pos = atomicAdd(&cursor[dst[e]], 1);
    csr_src[pos] = src[e];
    csr_g1[pos]  = expf(-0.5f * s1);
    csr_g2[pos]  = expf(-0.5f * s2);
}

// ---------------- h1 = features @ W1  [N,128]x[128,64] ----------------
__global__ __launch_bounds__(64) void gemm1_kernel(const float* __restrict__ x,
                                                   const float* __restrict__ W,
                                                   float* __restrict__ h) {
    __shared__ float xs[IN_FEATS];
    int n = blockIdx.x;
    int t = threadIdx.x;
    xs[t]      = x[n * IN_FEATS + t];
    xs[t + 64] = x[n * IN_FEATS + t + 64];
    __syncthreads();
    float acc = 0.f;
#pragma unroll
    for (int k = 0; k < IN_FEATS; ++k)
        acc += xs[k] * W[k * N_HIDDEN + t];
    h[n * N_HIDDEN + t] = acc;
}

// ---------------- agg1 + gemm2 fused: h2[n] = (sum g1*h1[src] + b1) @ W2 ----------------
// 256 threads = 4 waves; one wave per node; lane = hidden feature (64)
// N_NODES = 50000 = 12500*4 exactly, so every wave has a valid node (barrier-safe).
__global__ __launch_bounds__(256) void agg1_gemm2_kernel(const float* __restrict__ h,
                                                         const int* __restrict__ offsets,
                                                         const int* __restrict__ csr_src,
                                                         const float* __restrict__ csr_g,
                                                         const float* __restrict__ b,
                                                         const float* __restrict__ W2,
                                                         float* __restrict__ h2) {
    __shared__ float xs[4 * N_HIDDEN];
    int wid = threadIdx.x >> 6;
    int t   = threadIdx.x & 63;
    int n   = blockIdx.x * 4 + wid;
    int beg = offsets[n], end = offsets[n + 1];

    // 4-way unrolled gather: 4 independent load chains in flight
    float a0 = 0.f, a1 = 0.f, a2 = 0.f, a3 = 0.f;
    int j = beg;
    for (; j + 4 <= end; j += 4) {
        int   s0 = csr_src[j + 0]; float g0 = csr_g[j + 0];
        int   s1 = csr_src[j + 1]; float g1 = csr_g[j + 1];
        int   s2 = csr_src[j + 2]; float g2 = csr_g[j + 2];
        int   s3 = csr_src[j + 3]; float g3 = csr_g[j + 3];
        float v0 = h[(size_t)s0 * N_HIDDEN + t];
        float v1 = h[(size_t)s1 * N_HIDDEN + t];
        float v2 = h[(size_t)s2 * N_HIDDEN + t];
        float v3 = h[(size_t)s3 * N_HIDDEN + t];
        a0 += v0 * g0; a1 += v1 * g1; a2 += v2 * g2; a3 += v3 * g3;
    }
    for (; j < end; ++j)
        a0 += h[(size_t)csr_src[j] * N_HIDDEN + t] * csr_g[j];
    float x = (a0 + a1) + (a2 + a3) + b[t];

    xs[wid * N_HIDDEN + t] = x;
    __syncthreads();

    // h2 row = x1 row @ W2  (W2: [64,40], ~10 KB, L1-hot)
    if (t < OUT_FEATS) {
        const float* xr = &xs[wid * N_HIDDEN];
        float acc = 0.f;
#pragma unroll
        for (int k = 0; k < N_HIDDEN; ++k)
            acc += xr[k] * W2[k * OUT_FEATS + t];
        h2[(size_t)n * OUT_FEATS + t] = acc;
    }
}

// ---------------- agg layer 2 + b2 + log_softmax fused ----------------
__global__ __launch_bounds__(256) void agg2_kernel(const float* __restrict__ h,
                                                   const int* __restrict__ offsets,
                                                   const int* __restrict__ csr_src,
                                                   const float* __restrict__ csr_g,
                                                   const float* __restrict__ b,
                                                   float* __restrict__ out) {
    int n = blockIdx.x * 4 + (threadIdx.x >> 6);
    int t = threadIdx.x & 63;
    if (n >= N_NODES) return;
    int beg = offsets[n], end = offsets[n + 1];
    float a0 = 0.f, a1 = 0.f, a2 = 0.f, a3 = 0.f;
    if (t < OUT_FEATS) {
        int j = beg;
        for (; j + 4 <= end; j += 4) {
            int   s0 = csr_src[j + 0]; float g0 = csr_g[j + 0];
            int   s1 = csr_src[j + 1]; float g1 = csr_g[j + 1];
            int   s2 = csr_src[j + 2]; float g2 = csr_g[j + 2];
            int   s3 = csr_src[j + 3]; float g3 = csr_g[j + 3];
            float v0 = h[(size_t)s0 * OUT_FEATS + t];
            float v1 = h[(size_t)s1 * OUT_FEATS + t];
            float v2 = h[(size_t)s2 * OUT_FEATS + t];
            float v3 = h[(size_t)s3 * OUT_FEATS + t];
            a0 += v0 * g0; a1 += v1 * g1; a2 += v2 * g2; a3 += v3 * g3;
        }
        for (; j < end; ++j)
            a0 += h[(size_t)csr_src[j] * OUT_FEATS + t] * csr_g[j];
    }
    float acc = (a0 + a1) + (a2 + a3);

    float v = (t < OUT_FEATS) ? acc + b[t] : -INFINITY;
    float m = v;
#pragma unroll
    for (int off = 32; off; off >>= 1)
        m = fmaxf(m, __shfl_xor(m, off, 64));
    float ex = (t < OUT_FEATS) ? expf(v - m) : 0.f;
    float s = ex;
#pragma unroll
    for (int off = 32; off; off >>= 1)
        s += __shfl_xor(s, off, 64);
    if (t < OUT_FEATS)
        out[n * OUT_FEATS + t] = v - m - logf(s);
}

extern "C" void kernel_launch(void* const* d_in, const int* in_sizes, int n_in,
                              void* d_out, int out_size, void* d_ws, size_t ws_size,
                              hipStream_t stream) {
    const float* features    = (const float*)d_in[0];
    const float* edge_weight = (const float*)d_in[1];
    const int*   src         = (const int*)d_in[2];
    const int*   dst         = (const int*)d_in[3];
    const float* W1          = (const float*)d_in[4];
    const float* b1          = (const float*)d_in[5];
    const float* mu1         = (const float*)d_in[6];
    const float* is1         = (const float*)d_in[7];
    const float* W2          = (const float*)d_in[8];
    const float* b2          = (const float*)d_in[9];
    const float* mu2         = (const float*)d_in[10];
    const float* is2         = (const float*)d_in[11];
    float* out = (float*)d_out;

    // Workspace layout (4-byte elems):
    // h1[3.2M] h2[2M] csr_src[0.8M] csr_g1[0.8M] csr_g2[0.8M]
    // counts[50k] cursor[50k] offsets[50k+1] blkSums[196]
    float* ws = (float*)d_ws;
    float* h1      = ws;
    float* h2      = h1 + (size_t)N_NODES * N_HIDDEN;
    int*   csr_src = (int*)(h2 + (size_t)N_NODES * OUT_FEATS);
    float* csr_g1  = (float*)(csr_src + N_EDGES);
    float* csr_g2  = csr_g1 + N_EDGES;
    int*   counts  = (int*)(csr_g2 + N_EDGES);
    int*   cursor  = counts + N_NODES;
    int*   offsets = cursor + N_NODES;
    int*   blkSums = offsets + N_NODES + 1;

    // ---- CSR build ----
    hipMemsetAsync(counts, 0, N_NODES * sizeof(int), stream);
    hist_kernel<<<(N_EDGES + 255) / 256, 256, 0, stream>>>(dst, counts);
    scan_blk_kernel<<<SCAN_NB, 256, 0, stream>>>(counts, offsets, blkSums);
    scan_top_kernel<<<1, 256, 0, stream>>>(blkSums);
    scan_add_kernel<<<SCAN_NB, 256, 0, stream>>>(offsets, blkSums, cursor);
    fill_kernel<<<(N_EDGES + 255) / 256, 256, 0, stream>>>(src, dst, edge_weight,
                                                           mu1, is1, mu2, is2,
                                                           cursor, csr_src, csr_g1, csr_g2);

    // ---- layer 1 (+ fused layer-2 GEMM) ----
    gemm1_kernel<<<N_NODES, 64, 0, stream>>>(features, W1, h1);
    agg1_gemm2_kernel<<<N_NODES / 4, 256, 0, stream>>>(h1, offsets, csr_src, csr_g1,
                                                       b1, W2, h2);

    // ---- layer 2 aggregation + epilogue ----
    agg2_kernel<<<(N_NODES + 3) / 4, 256, 0, stream>>>(h2, offsets, csr_src, csr_g2, b2, out);
}

// Round 5
// 326.712 us; speedup vs baseline: 1.6526x; 1.0250x over previous
//
#include <hip/hip_runtime.h>
#include <math.h>

#define N_NODES 50000
#define N_EDGES 800000
#define IN_FEATS 128
#define N_HIDDEN 64
#define OUT_FEATS 40
#define DIM 8
#define SCAN_NB ((N_NODES + 255) / 256)   // 196

// ---------------- wave-wide inclusive scan (64 lanes) ----------------
__device__ __forceinline__ int wave_incl_scan(int x, int lane) {
#pragma unroll
    for (int off = 1; off < 64; off <<= 1) {
        int v = __shfl_up(x, off, 64);
        if (lane >= off) x += v;
    }
    return x;
}

// ---------------- CSR build: in-degree histogram ----------------
__global__ void hist_kernel(const int* __restrict__ dst, int* __restrict__ counts) {
    int e = blockIdx.x * blockDim.x + threadIdx.x;
    if (e < N_EDGES) atomicAdd(&counts[dst[e]], 1);
}

// ---------------- scan phase 1: block-local exclusive scan + block totals ----------------
__global__ __launch_bounds__(256) void scan_blk_kernel(const int* __restrict__ counts,
                                                       int* __restrict__ offsets,
                                                       int* __restrict__ blkSums) {
    int i = blockIdx.x * 256 + threadIdx.x;
    int lane = threadIdx.x & 63, wid = threadIdx.x >> 6;
    int x = (i < N_NODES) ? counts[i] : 0;
    int incl = wave_incl_scan(x, lane);
    __shared__ int wsum[4];
    if (lane == 63) wsum[wid] = incl;
    __syncthreads();
    int base = 0;
#pragma unroll
    for (int w = 0; w < 4; ++w)
        if (w < wid) base += wsum[w];
    if (i < N_NODES) offsets[i] = base + incl - x;     // block-local exclusive
    if (threadIdx.x == 255) blkSums[blockIdx.x] = base + incl;  // block total
}

// ---------------- scan phase 2: exclusive scan of 196 block totals ----------------
__global__ __launch_bounds__(256) void scan_top_kernel(int* __restrict__ blkSums) {
    int i = threadIdx.x;
    int lane = i & 63, wid = i >> 6;
    int x = (i < SCAN_NB) ? blkSums[i] : 0;
    int incl = wave_incl_scan(x, lane);
    __shared__ int wsum[4];
    if (lane == 63) wsum[wid] = incl;
    __syncthreads();
    int base = 0;
#pragma unroll
    for (int w = 0; w < 4; ++w)
        if (w < wid) base += wsum[w];
    if (i < SCAN_NB) blkSums[i] = base + incl - x;     // exclusive
}

// ---------------- scan phase 3: add block bases, emit offsets + cursor ----------------
__global__ __launch_bounds__(256) void scan_add_kernel(int* __restrict__ offsets,
                                                       const int* __restrict__ blkSums,
                                                       int* __restrict__ cursor) {
    int i = blockIdx.x * 256 + threadIdx.x;
    if (i < N_NODES) {
        int v = offsets[i] + blkSums[blockIdx.x];
        offsets[i] = v;
        cursor[i]  = v;
    }
    if (blockIdx.x == 0 && threadIdx.x == 0)
        offsets[N_NODES] = N_EDGES;
}

// ---------------- CSR fill: ONE 16B struct store per edge {src, g1, g2, 0} ----------------
__global__ void fill_kernel(const int* __restrict__ src, const int* __restrict__ dst,
                            const float* __restrict__ ew,
                            const float* __restrict__ mu1, const float* __restrict__ is1,
                            const float* __restrict__ mu2, const float* __restrict__ is2,
                            int* __restrict__ cursor,
                            float4* __restrict__ csr_ef) {
    int e = blockIdx.x * blockDim.x + threadIdx.x;
    if (e >= N_EDGES) return;
    float s1 = 0.f, s2 = 0.f;
#pragma unroll
    for (int d = 0; d < DIM; ++d) {
        float v = ew[e * DIM + d];
        float d1 = v - mu1[d]; float a1 = is1[d];
        float d2 = v - mu2[d]; float a2 = is2[d];
        s1 += d1 * d1 * a1 * a1;
        s2 += d2 * d2 * a2 * a2;
    }
    int pos = atomicAdd(&cursor[dst[e]], 1);
    float4 v;
    v.x = __int_as_float(src[e]);
    v.y = expf(-0.5f * s1);
    v.z = expf(-0.5f * s2);
    v.w = 0.f;
    csr_ef[pos] = v;
}

// ---------------- h1 = features @ W1  [N,128]x[128,64] ----------------
// 256 threads = 4 waves; wave = 4 nodes; lane = ns*16 + f4 (4 output feats per lane)
// float4 W loads; x rows staged in wave-private LDS (padded stride 132 -> no conflicts)
__global__ __launch_bounds__(256) void gemm1_kernel(const float* __restrict__ x,
                                                    const float* __restrict__ W,
                                                    float* __restrict__ h) {
    __shared__ float xs[4][4][132];
    int wid = threadIdx.x >> 6, lane = threadIdx.x & 63;
    int ns = lane >> 4, f4 = lane & 15;
    int nodeBase = blockIdx.x * 16 + wid * 4;
    // stage 4 x-rows (512 floats) with 8 coalesced iterations
#pragma unroll
    for (int i = 0; i < 8; ++i) {
        int idx = lane + i * 64;
        int nn = idx >> 7, k = idx & 127;
        xs[wid][nn][k] = x[(size_t)(nodeBase + nn) * IN_FEATS + k];
    }
    const float4* W4 = (const float4*)W;   // W4[k*16 + f4] = W[k][4*f4 .. 4*f4+3]
    float4 acc = make_float4(0.f, 0.f, 0.f, 0.f);
#pragma unroll 4
    for (int k = 0; k < IN_FEATS; ++k) {
        float xv = xs[wid][ns][k];
        float4 w = W4[k * 16 + f4];
        acc.x += xv * w.x; acc.y += xv * w.y;
        acc.z += xv * w.z; acc.w += xv * w.w;
    }
    int n = nodeBase + ns;
    ((float4*)h)[((size_t)n * N_HIDDEN + 4 * f4) >> 2] = acc;
}

// ---------------- agg1 + gemm2 fused: h2[n] = (sum g1*h1[src] + b1) @ W2 ----------------
// 256 threads = 4 waves; one wave per node; lane = hidden feature (64)
__global__ __launch_bounds__(256) void agg1_gemm2_kernel(const float* __restrict__ h,
                                                         const int* __restrict__ offsets,
                                                         const float4* __restrict__ csr,
                                                         const float* __restrict__ b,
                                                         const float* __restrict__ W2,
                                                         float* __restrict__ h2) {
    __shared__ float xs[4 * N_HIDDEN];
    int wid = threadIdx.x >> 6;
    int t   = threadIdx.x & 63;
    int n   = blockIdx.x * 4 + wid;
    int beg = offsets[n], end = offsets[n + 1];

    float a0 = 0.f, a1 = 0.f, a2 = 0.f, a3 = 0.f;
    int j = beg;
    for (; j + 8 <= end; j += 8) {
        float4 c0 = csr[j + 0], c1 = csr[j + 1], c2 = csr[j + 2], c3 = csr[j + 3];
        float4 c4 = csr[j + 4], c5 = csr[j + 5], c6 = csr[j + 6], c7 = csr[j + 7];
        float v0 = h[(size_t)__float_as_int(c0.x) * N_HIDDEN + t];
        float v1 = h[(size_t)__float_as_int(c1.x) * N_HIDDEN + t];
        float v2 = h[(size_t)__float_as_int(c2.x) * N_HIDDEN + t];
        float v3 = h[(size_t)__float_as_int(c3.x) * N_HIDDEN + t];
        float v4 = h[(size_t)__float_as_int(c4.x) * N_HIDDEN + t];
        float v5 = h[(size_t)__float_as_int(c5.x) * N_HIDDEN + t];
        float v6 = h[(size_t)__float_as_int(c6.x) * N_HIDDEN + t];
        float v7 = h[(size_t)__float_as_int(c7.x) * N_HIDDEN + t];
        a0 += v0 * c0.y; a1 += v1 * c1.y; a2 += v2 * c2.y; a3 += v3 * c3.y;
        a0 += v4 * c4.y; a1 += v5 * c5.y; a2 += v6 * c6.y; a3 += v7 * c7.y;
    }
    for (; j + 4 <= end; j += 4) {
        float4 c0 = csr[j + 0], c1 = csr[j + 1], c2 = csr[j + 2], c3 = csr[j + 3];
        float v0 = h[(size_t)__float_as_int(c0.x) * N_HIDDEN + t];
        float v1 = h[(size_t)__float_as_int(c1.x) * N_HIDDEN + t];
        float v2 = h[(size_t)__float_as_int(c2.x) * N_HIDDEN + t];
        float v3 = h[(size_t)__float_as_int(c3.x) * N_HIDDEN + t];
        a0 += v0 * c0.y; a1 += v1 * c1.y; a2 += v2 * c2.y; a3 += v3 * c3.y;
    }
    for (; j < end; ++j) {
        float4 c = csr[j];
        a0 += h[(size_t)__float_as_int(c.x) * N_HIDDEN + t] * c.y;
    }
    float x = (a0 + a1) + (a2 + a3) + b[t];

    xs[wid * N_HIDDEN + t] = x;   // wave-private region: no __syncthreads needed
    if (t < OUT_FEATS) {
        const float* xr = &xs[wid * N_HIDDEN];
        float acc = 0.f;
#pragma unroll
        for (int k = 0; k < N_HIDDEN; ++k)
            acc += xr[k] * W2[k * OUT_FEATS + t];
        h2[(size_t)n * OUT_FEATS + t] = acc;
    }
}

// ---------------- agg layer 2 + b2 + log_softmax fused ----------------
__global__ __launch_bounds__(256) void agg2_kernel(const float* __restrict__ h,
                                                   const int* __restrict__ offsets,
                                                   const float4* __restrict__ csr,
                                                   const float* __restrict__ b,
                                                   float* __restrict__ out) {
    int n = blockIdx.x * 4 + (threadIdx.x >> 6);
    int t = threadIdx.x & 63;
    if (n >= N_NODES) return;
    int tc = (t < OUT_FEATS) ? t : (OUT_FEATS - 1);   // clamp: no divergence, no OOB
    int beg = offsets[n], end = offsets[n + 1];
    float a0 = 0.f, a1 = 0.f, a2 = 0.f, a3 = 0.f;
    int j = beg;
    for (; j + 8 <= end; j += 8) {
        float4 c0 = csr[j + 0], c1 = csr[j + 1], c2 = csr[j + 2], c3 = csr[j + 3];
        float4 c4 = csr[j + 4], c5 = csr[j + 5], c6 = csr[j + 6], c7 = csr[j + 7];
        float v0 = h[(size_t)__float_as_int(c0.x) * OUT_FEATS + tc];
        float v1 = h[(size_t)__float_as_int(c1.x) * OUT_FEATS + tc];
        float v2 = h[(size_t)__float_as_int(c2.x) * OUT_FEATS + tc];
        float v3 = h[(size_t)__float_as_int(c3.x) * OUT_FEATS + tc];
        float v4 = h[(size_t)__float_as_int(c4.x) * OUT_FEATS + tc];
        float v5 = h[(size_t)__float_as_int(c5.x) * OUT_FEATS + tc];
        float v6 = h[(size_t)__float_as_int(c6.x) * OUT_FEATS + tc];
        float v7 = h[(size_t)__float_as_int(c7.x) * OUT_FEATS + tc];
        a0 += v0 * c0.z; a1 += v1 * c1.z; a2 += v2 * c2.z; a3 += v3 * c3.z;
        a0 += v4 * c4.z; a1 += v5 * c5.z; a2 += v6 * c6.z; a3 += v7 * c7.z;
    }
    for (; j + 4 <= end; j += 4) {
        float4 c0 = csr[j + 0], c1 = csr[j + 1], c2 = csr[j + 2], c3 = csr[j + 3];
        float v0 = h[(size_t)__float_as_int(c0.x) * OUT_FEATS + tc];
        float v1 = h[(size_t)__float_as_int(c1.x) * OUT_FEATS + tc];
        float v2 = h[(size_t)__float_as_int(c2.x) * OUT_FEATS + tc];
        float v3 = h[(size_t)__float_as_int(c3.x) * OUT_FEATS + tc];
        a0 += v0 * c0.z; a1 += v1 * c1.z; a2 += v2 * c2.z; a3 += v3 * c3.z;
    }
    for (; j < end; ++j) {
        float4 c = csr[j];
        a0 += h[(size_t)__float_as_int(c.x) * OUT_FEATS + tc] * c.z;
    }
    float acc = (a0 + a1) + (a2 + a3);

    float v = (t < OUT_FEATS) ? acc + b[t] : -INFINITY;
    float m = v;
#pragma unroll
    for (int off = 32; off; off >>= 1)
        m = fmaxf(m, __shfl_xor(m, off, 64));
    float ex = (t < OUT_FEATS) ? expf(v - m) : 0.f;
    float s = ex;
#pragma unroll
    for (int off = 32; off; off >>= 1)
        s += __shfl_xor(s, off, 64);
    if (t < OUT_FEATS)
        out[n * OUT_FEATS + t] = v - m - logf(s);
}

extern "C" void kernel_launch(void* const* d_in, const int* in_sizes, int n_in,
                              void* d_out, int out_size, void* d_ws, size_t ws_size,
                              hipStream_t stream) {
    const float* features    = (const float*)d_in[0];
    const float* edge_weight = (const float*)d_in[1];
    const int*   src         = (const int*)d_in[2];
    const int*   dst         = (const int*)d_in[3];
    const float* W1          = (const float*)d_in[4];
    const float* b1          = (const float*)d_in[5];
    const float* mu1         = (const float*)d_in[6];
    const float* is1         = (const float*)d_in[7];
    const float* W2          = (const float*)d_in[8];
    const float* b2          = (const float*)d_in[9];
    const float* mu2         = (const float*)d_in[10];
    const float* is2         = (const float*)d_in[11];
    float* out = (float*)d_out;

    // Workspace layout (16B-aligned first):
    // csr_ef float4[800k] (12.8MB) | h1[3.2M f] | h2[2M f] | counts | cursor | offsets | blkSums
    float4* csr_ef = (float4*)d_ws;
    float*  h1     = (float*)(csr_ef + N_EDGES);
    float*  h2     = h1 + (size_t)N_NODES * N_HIDDEN;
    int*    counts = (int*)(h2 + (size_t)N_NODES * OUT_FEATS);
    int*    cursor = counts + N_NODES;
    int*    offsets= cursor + N_NODES;
    int*    blkSums= offsets + N_NODES + 1;

    // ---- CSR build ----
    hipMemsetAsync(counts, 0, N_NODES * sizeof(int), stream);
    hist_kernel<<<(N_EDGES + 255) / 256, 256, 0, stream>>>(dst, counts);
    scan_blk_kernel<<<SCAN_NB, 256, 0, stream>>>(counts, offsets, blkSums);
    scan_top_kernel<<<1, 256, 0, stream>>>(blkSums);
    scan_add_kernel<<<SCAN_NB, 256, 0, stream>>>(offsets, blkSums, cursor);
    fill_kernel<<<(N_EDGES + 255) / 256, 256, 0, stream>>>(src, dst, edge_weight,
                                                           mu1, is1, mu2, is2,
                                                           cursor, csr_ef);

    // ---- layer 1 (+ fused layer-2 GEMM) ----
    gemm1_kernel<<<N_NODES / 16, 256, 0, stream>>>(features, W1, h1);
    agg1_gemm2_kernel<<<N_NODES / 4, 256, 0, stream>>>(h1, offsets, csr_ef, b1, W2, h2);

    // ---- layer 2 aggregation + epilogue ----
    agg2_kernel<<<(N_NODES + 3) / 4, 256, 0, stream>>>(h2, offsets, csr_ef, b2, out);
}